// Round 9
// baseline (131.387 us; speedup 1.0000x reference)
//
#include <hip/hip_runtime.h>
#include <hip/hip_bf16.h>
#include <stdint.h>

#define BB 32
#define NN 1024
#define MM 1024
#define DD 256

typedef __attribute__((ext_vector_type(8))) short short8;
typedef __attribute__((ext_vector_type(4))) float floatx4;

__device__ inline unsigned short f2bf(float x) {
    union { __hip_bfloat16 h; unsigned short u; } cv;
    cv.h = __float2bfloat16(x);
    return cv.u;
}
__device__ inline short8 pack8(float4 a, float4 b) {
    short8 o;
    o[0] = f2bf(a.x); o[1] = f2bf(a.y); o[2] = f2bf(a.z); o[3] = f2bf(a.w);
    o[4] = f2bf(b.x); o[5] = f2bf(b.y); o[6] = f2bf(b.z); o[7] = f2bf(b.w);
    return o;
}
// async global->LDS, 16B/lane. LDS dest = wave-uniform base + lane*16.
__device__ inline void async_copy16(void* lds, const void* g) {
    __builtin_amdgcn_global_load_lds(
        (const __attribute__((address_space(1))) unsigned int*)g,
        (__attribute__((address_space(3))) unsigned int*)lds, 16, 0, 0);
}

// ---------------------------------------------------------------------------
// Fully fused: fp32 inputs -> (in-reg bf16 convert) -> batched GEMM ->
// norms as a by-product of fragment reads -> Hausdorff mins -> plain stores.
// Grid (32 batches, 8 n-tiles), 512 thr = 8 waves (2n x 4m; 64n x 32m each),
// 1 block/CU (136 KB LDS). A panel fp32 staged once -> af bf16 regs + sq1.
// B streamed fp32 [128m][64k] 32 KB chunks, ring-4, counted vmcnt, one
// barrier/step. sq2 accumulated from the B fragment fp32 values (free).
// No global atomics anywhere: rowmin block-exclusive, colmin -> colpart.
// ---------------------------------------------------------------------------
__global__ __launch_bounds__(512, 2) void gemm_kernel(
        const float* __restrict__ h1, const float* __restrict__ h2,
        unsigned int* __restrict__ rowmin, unsigned int* __restrict__ colpart) {
    __shared__ __align__(16) char pool[136192];
    // [0,128K): A fp32 panel (prologue), then B ring BUF0..3 @ 0/32K/64K/96K
    float*        sq1_lds = (float*)(pool + 131072);        // 512 B
    unsigned int* cl      = (unsigned int*)(pool + 131584); // 4 KB colmin
    unsigned int* rlds    = (unsigned int*)(pool + 135680); // 512 B rowmin

    const int b    = blockIdx.x;      // batch; all 8 tiles of b on XCD b%8
    const int tile = blockIdx.y;      // n-tile 0..7
    const int n0   = tile * 128;

    const int tid  = threadIdx.x;
    const int wave = tid >> 6;        // 0..7
    const int lane = tid & 63;
    const int wn   = (wave >> 2) * 64;    // {0,64}
    const int wm   = (wave & 3) * 32;     // {0,32,64,96}

    const int krow = lane >> 4;   // 0..3
    const int rrow = lane & 15;   // 0..15
    const int rx   = rrow & 7;
    const int lrow = krow * 4;
    const int lcol = rrow;

    const char* Ag = (const char*)(h1 + ((size_t)b * NN + n0) * DD); // 1KB rows
    const char* Bg = (const char*)(h2 + (size_t)b * MM * DD);        // 1KB rows

    // LDS min-buffer inits (plain ds_writes; drained before barrier 1)
    cl[tid] = 0x7F800000u; cl[tid + 512] = 0x7F800000u;
    if (tid < 128) rlds[tid] = 0x7F800000u;

    // ---- stage A panel: 128 rows x 1 KB fp32, 16 rows/wave, swizzled src ----
    #pragma unroll
    for (int t = 0; t < 16; ++t) {
        int r = t * 8 + wave;
        async_copy16(pool + r * 1024,
                     Ag + (size_t)r * 1024 + ((lane ^ ((r & 7) << 1)) << 4));
    }
    asm volatile("s_waitcnt vmcnt(0) lgkmcnt(0)" ::: "memory");
    __builtin_amdgcn_s_barrier();
    __builtin_amdgcn_sched_barrier(0);

    // ---- A fp32 -> af bf16 regs; sq1 by-product (waves 0 and 4 only) ----
    short8 af[4][8];
    {
        float ssum[4] = {0.f, 0.f, 0.f, 0.f};
        #pragma unroll
        for (int i = 0; i < 4; ++i) {
            const char* rp = pool + (size_t)(wn + i * 16 + rrow) * 1024;
            #pragma unroll
            for (int kq = 0; kq < 8; ++kq) {
                int u0 = ((kq << 3) + (krow << 1)) ^ (rx << 1);
                float4 f0 = *(const float4*)(rp + (u0 << 4));
                float4 f1 = *(const float4*)(rp + ((u0 | 1) << 4));
                af[i][kq] = pack8(f0, f1);
                if ((wave & 3) == 0)
                    ssum[i] += f0.x*f0.x + f0.y*f0.y + f0.z*f0.z + f0.w*f0.w
                             + f1.x*f1.x + f1.y*f1.y + f1.z*f1.z + f1.w*f1.w;
            }
        }
        if ((wave & 3) == 0) {
            #pragma unroll
            for (int i = 0; i < 4; ++i) {
                float s = ssum[i];
                s += __shfl_xor(s, 16, 64);
                s += __shfl_xor(s, 32, 64);
                if (lane < 16) sq1_lds[wn + i * 16 + rrow] = s;
            }
        }
    }
    asm volatile("s_waitcnt lgkmcnt(0)" ::: "memory");
    __builtin_amdgcn_sched_barrier(0);
    __builtin_amdgcn_s_barrier();
    __builtin_amdgcn_sched_barrier(0);

    // ---- B chunk stager: fp32 [128m][64k] = 32 KB = 32 chunks of 1 KB ----
    const int rl4 = lane >> 4;          // row within 1 KB chunk (4 rows)
    const int pu  = lane & 15;          // physical 16B unit
    #define STAGE(mt_, ks_, boff_)                                            \
        { _Pragma("unroll")                                                   \
          for (int c = 0; c < 4; ++c) {                                       \
            int ch_ = wave * 4 + c;                                           \
            int r_  = ch_ * 4 + rl4;                                          \
            async_copy16(pool + (boff_) + ch_ * 1024,                         \
                Bg + (size_t)((mt_) * 128 + r_) * 1024 + (size_t)(ks_) * 256  \
                   + ((pu ^ ((r_ & 7) << 1)) << 4)); } }

    STAGE(0, 0, 0); STAGE(0, 1, 32768); STAGE(0, 2, 65536);

    float rmin[4][4];
    #pragma unroll
    for (int i = 0; i < 4; ++i)
        #pragma unroll
        for (int r = 0; r < 4; ++r) rmin[i][r] = 3.0e38f;
    float s2a0 = 0.f, s2a1 = 0.f;

    // ---- main loop: 32 steps (8 mt x 4 ks); waits 8/8/4/0; stage s+3 ----
    #pragma unroll 1
    for (int mt = 0; mt < 8; ++mt) {
        floatx4 acc[4][2] = {};

        #pragma unroll
        for (int ks = 0; ks < 4; ++ks) {
            if (mt == 7 && ks == 2)      { asm volatile("s_waitcnt vmcnt(4)" ::: "memory"); }
            else if (mt == 7 && ks == 3) { asm volatile("s_waitcnt vmcnt(0)" ::: "memory"); }
            else                         { asm volatile("s_waitcnt vmcnt(8)" ::: "memory"); }
            __builtin_amdgcn_s_barrier();
            __builtin_amdgcn_sched_barrier(0);

            if (ks == 0)          { STAGE(mt,     3, 98304); }
            else if (mt < 7) {
                if (ks == 1)      { STAGE(mt + 1, 0, 0);     }
                else if (ks == 2) { STAGE(mt + 1, 1, 32768); }
                else              { STAGE(mt + 1, 2, 65536); }
            }

            const char* Bb = pool + ((ks == 0) ? 0 : (ks == 1) ? 32768
                                   : (ks == 2) ? 65536 : 98304);
            __builtin_amdgcn_s_setprio(1);
            #pragma unroll
            for (int kk = 0; kk < 2; ++kk) {
                #pragma unroll
                for (int j = 0; j < 2; ++j) {
                    const char* rp = Bb + (size_t)(wm + j * 16 + rrow) * 256;
                    int v0 = (((kk << 2) + krow) << 1) ^ (rx << 1);
                    float4 g0 = *(const float4*)(rp + (v0 << 4));
                    float4 g1 = *(const float4*)(rp + ((v0 | 1) << 4));
                    short8 bv = pack8(g0, g1);
                    #pragma unroll
                    for (int i = 0; i < 4; ++i)
                        acc[i][j] = __builtin_amdgcn_mfma_f32_16x16x32_bf16(
                            af[i][ks * 2 + kk], bv, acc[i][j], 0, 0, 0);
                    float d = g0.x*g0.x + g0.y*g0.y + g0.z*g0.z + g0.w*g0.w
                            + g1.x*g1.x + g1.y*g1.y + g1.z*g1.z + g1.w*g1.w;
                    if (j == 0) s2a0 += d; else s2a1 += d;
                }
            }
            __builtin_amdgcn_s_setprio(0);
        }

        // ---- per-mt epilogue: norms + dist + mins (regs + LDS only) ----
        float s20 = s2a0; s20 += __shfl_xor(s20, 16, 64); s20 += __shfl_xor(s20, 32, 64);
        float s21 = s2a1; s21 += __shfl_xor(s21, 16, 64); s21 += __shfl_xor(s21, 32, 64);
        s2a0 = 0.f; s2a1 = 0.f;

        float cmin0 = 3.0e38f, cmin1 = 3.0e38f;
        #pragma unroll
        for (int i = 0; i < 4; ++i) {
            float4 s1q = *(const float4*)((const char*)sq1_lds
                        + ((wn + i * 16 + lrow) << 2));
            #pragma unroll
            for (int r = 0; r < 4; ++r) {
                float s1x = ((const float*)&s1q)[r];
                float d0 = fmaxf(s1x + s20 - 2.0f * acc[i][0][r], 0.0f);
                float d1 = fmaxf(s1x + s21 - 2.0f * acc[i][1][r], 0.0f);
                rmin[i][r] = fminf(rmin[i][r], fminf(d0, d1));
                cmin0 = fminf(cmin0, d0);
                cmin1 = fminf(cmin1, d1);
            }
        }
        cmin0 = fminf(cmin0, __shfl_xor(cmin0, 16, 64));
        cmin0 = fminf(cmin0, __shfl_xor(cmin0, 32, 64));
        cmin1 = fminf(cmin1, __shfl_xor(cmin1, 16, 64));
        cmin1 = fminf(cmin1, __shfl_xor(cmin1, 32, 64));
        if (lane < 16) {
            atomicMin(&cl[mt * 128 + wm + lcol],      __float_as_uint(cmin0));
            atomicMin(&cl[mt * 128 + wm + 16 + lcol], __float_as_uint(cmin1));
        }
    }

    // ---- rowmin: combine 4 m-wave-groups via LDS, then plain store ----
    #pragma unroll
    for (int i = 0; i < 4; ++i) {
        #pragma unroll
        for (int r = 0; r < 4; ++r) {
            float v = rmin[i][r];
            #pragma unroll
            for (int off = 1; off < 16; off <<= 1)
                v = fminf(v, __shfl_xor(v, off, 64));
            if (lcol == 0)
                atomicMin(&rlds[wn + i * 16 + lrow + r], __float_as_uint(v));
        }
    }
    __syncthreads();

    unsigned int* cp = colpart + ((size_t)b * 8 + tile) * 1024;
    cp[tid]       = cl[tid];
    cp[tid + 512] = cl[tid + 512];
    if (tid < 128) rowmin[b * NN + n0 + tid] = rlds[tid];
    #undef STAGE
}

// ---------------------------------------------------------------------------
// out[b] = (sum_n rowmin + sum_m min_tile colpart) / 1024
// ---------------------------------------------------------------------------
__global__ __launch_bounds__(256) void finalize_kernel(
        const unsigned int* __restrict__ rowmin,
        const unsigned int* __restrict__ colpart,
        float* __restrict__ out) {
    int b = blockIdx.x;
    int tid = threadIdx.x;
    float s = 0.0f;
    #pragma unroll
    for (int t = 0; t < 4; ++t) {
        int m = tid + t * 256;
        s += __uint_as_float(rowmin[b * NN + m]);
        unsigned int v = colpart[(size_t)b * 8192 + m];
        #pragma unroll
        for (int q = 1; q < 8; ++q)
            v = min(v, colpart[(size_t)b * 8192 + q * 1024 + m]);
        s += __uint_as_float(v);
    }
    #pragma unroll
    for (int off = 32; off; off >>= 1) s += __shfl_xor(s, off, 64);
    __shared__ float wsum[4];
    if ((tid & 63) == 0) wsum[tid >> 6] = s;
    __syncthreads();
    if (tid == 0) out[b] = (wsum[0] + wsum[1] + wsum[2] + wsum[3]) * (1.0f / 1024.0f);
}

// ---------------------------------------------------------------------------
extern "C" void kernel_launch(void* const* d_in, const int* in_sizes, int n_in,
                              void* d_out, int out_size, void* d_ws, size_t ws_size,
                              hipStream_t stream) {
    const float* h1 = (const float*)d_in[0];
    const float* h2 = (const float*)d_in[1];
    float* out = (float*)d_out;

    unsigned int* rowmin  = (unsigned int*)d_ws;          // 32*1024 u32 (128 KB)
    unsigned int* colpart = rowmin + BB * NN;             // 32*8*1024 u32 (1 MB)

    hipLaunchKernelGGL(gemm_kernel, dim3(BB, 8), dim3(512), 0, stream,
                       h1, h2, rowmin, colpart);

    hipLaunchKernelGGL(finalize_kernel, dim3(BB), dim3(256), 0, stream,
                       rowmin, colpart, out);
}

// Round 10
// 48.638 us; speedup vs baseline: 2.7013x; 2.7013x over previous
//
#include <hip/hip_runtime.h>
#include <hip/hip_bf16.h>
#include <stdint.h>

#define BB 32
#define NN 1024
#define MM 1024
#define DD 256

typedef __attribute__((ext_vector_type(8))) short short8;
typedef __attribute__((ext_vector_type(4))) float floatx4;

__device__ inline unsigned short f2bf(float x) {
    union { __hip_bfloat16 h; unsigned short u; } cv;
    cv.h = __float2bfloat16(x);
    return cv.u;
}
__device__ inline short8 pack8(float4 a, float4 b) {
    short8 o;
    o[0] = f2bf(a.x); o[1] = f2bf(a.y); o[2] = f2bf(a.z); o[3] = f2bf(a.w);
    o[4] = f2bf(b.x); o[5] = f2bf(b.y); o[6] = f2bf(b.z); o[7] = f2bf(b.w);
    return o;
}
// async global->LDS. LDS dest = wave-uniform base; HW adds lane*size.
__device__ inline void async_copy16(void* lds, const void* g) {
    __builtin_amdgcn_global_load_lds(
        (const __attribute__((address_space(1))) unsigned int*)g,
        (__attribute__((address_space(3))) unsigned int*)lds, 16, 0, 0);
}
__device__ inline void async_copy4(void* lds, const void* g) {
    __builtin_amdgcn_global_load_lds(
        (const __attribute__((address_space(1))) unsigned int*)g,
        (__attribute__((address_space(3))) unsigned int*)lds, 4, 0, 0);
}

// ---------------------------------------------------------------------------
// Convert h2 only: fp32 -> bf16 + per-row sum of squares (fp32 exact).
// One wave per TWO rows (32 B/lane). 32768 rows -> 4096 blocks.
// ---------------------------------------------------------------------------
__global__ __launch_bounds__(256) void convert_kernel(
        const float* __restrict__ h2, unsigned short* __restrict__ h2b,
        float* __restrict__ sq2) {
    int wid  = blockIdx.x * 4 + (threadIdx.x >> 6);
    int lane = threadIdx.x & 63;
    int l5   = lane & 31;
    int row  = wid * 2 + (lane >> 5);

    const float4* p = (const float4*)(h2 + (size_t)row * DD) + l5 * 2;
    float4 a = p[0], c = p[1];

    float s = a.x*a.x + a.y*a.y + a.z*a.z + a.w*a.w
            + c.x*c.x + c.y*c.y + c.z*c.z + c.w*c.w;
    #pragma unroll
    for (int off = 16; off; off >>= 1) s += __shfl_xor(s, off, 64);

    *(short8*)((char*)(h2b + (size_t)row * DD) + l5 * 16) = pack8(a, c);
    if (l5 == 0) sq2[row] = s;
}

// ---------------------------------------------------------------------------
// A-resident batched GEMM + fused Hausdorff, BIG-chunk amortization.
// Grid (32 b, 8 n-tiles) = 256 blocks (1/CU), 512 thr = 8 waves (2n x 4m;
// wave tile 64n x 32m). Prologue: A panel 128x256 fp32 -> LDS -> af bf16
// regs + sq1 by-product; A region then becomes the B ring (staged AFTER
// extraction). Main loop: 8 steps, one per 128m x 256k bf16 B slice
// (64 KB, ring-2): 64 MFMA/wave between two barriers, counted vmcnt,
// stage = only in-loop vmem. No global atomics (plain stores).
// ---------------------------------------------------------------------------
__global__ __launch_bounds__(512, 2) void gemm_kernel(
        const float* __restrict__ h1, const unsigned short* __restrict__ h2b,
        const float* __restrict__ sq2,
        unsigned int* __restrict__ rowmin, unsigned int* __restrict__ colpart) {
    __shared__ __align__(16) char pool[131072];   // A panel, then B ring
    __shared__ __align__(16) float  sq1_s[128];
    __shared__ __align__(16) float  sq2_s[1024];
    __shared__ unsigned int cl_s[1024];
    __shared__ unsigned int rl_s[128];

    const int b    = blockIdx.x;      // batch; all 8 tiles of b on XCD b%8
    const int tile = blockIdx.y;      // n-tile 0..7
    const int n0   = tile * 128;

    const int tid  = threadIdx.x;
    const int wave = tid >> 6;        // 0..7
    const int lane = tid & 63;
    const int wn   = (wave >> 2) * 64;    // {0,64}
    const int wm   = (wave & 3) * 32;     // {0,32,64,96}

    const int krow = lane >> 4;   // 0..3
    const int rrow = lane & 15;   // 0..15
    const int rx   = rrow & 7;
    const int lrow = krow * 4;
    const int lcol = rrow;

    const char* Ag = (const char*)(h1 + ((size_t)b * NN + n0) * DD);  // 1KB rows
    const char* Bg = (const char*)(h2b + (size_t)b * MM * DD);        // 512B rows

    // LDS inits (plain ds ops; complete before first barrier via lgkm drain)
    cl_s[tid] = 0x7F800000u; cl_s[tid + 512] = 0x7F800000u;
    if (tid < 128) rl_s[tid] = 0x7F800000u;

    // ---- prologue vmem: sq2 (2 copies) then A panel (16 copies) ----
    #pragma unroll
    for (int t = 0; t < 2; ++t)
        async_copy4((char*)sq2_s + t * 2048 + wave * 256,
                    (const char*)(sq2 + b * MM) + t * 2048 + wave * 256 + lane * 4);
    #pragma unroll
    for (int t = 0; t < 16; ++t) {
        int r = t * 8 + wave;
        async_copy16(pool + r * 1024,
                     Ag + (size_t)r * 1024 + ((lane ^ (r & 7)) << 4));
    }
    asm volatile("s_waitcnt vmcnt(0) lgkmcnt(0)" ::: "memory");
    __builtin_amdgcn_s_barrier();
    __builtin_amdgcn_sched_barrier(0);

    // ---- A fp32 -> af bf16 regs; sq1 by-product (waves 0,4 only) ----
    short8 af[4][8];
    {
        float ssum[4] = {0.f, 0.f, 0.f, 0.f};
        #pragma unroll
        for (int i = 0; i < 4; ++i) {
            const char* rp = pool + (size_t)(wn + i * 16 + rrow) * 1024;
            #pragma unroll
            for (int kq = 0; kq < 8; ++kq) {
                int u0 = kq * 8 + krow * 2;
                float4 f0 = *(const float4*)(rp + ((u0 ^ rx) << 4));
                float4 f1 = *(const float4*)(rp + (((u0 + 1) ^ rx) << 4));
                af[i][kq] = pack8(f0, f1);
                if ((wave & 3) == 0)
                    ssum[i] += f0.x*f0.x + f0.y*f0.y + f0.z*f0.z + f0.w*f0.w
                             + f1.x*f1.x + f1.y*f1.y + f1.z*f1.z + f1.w*f1.w;
            }
        }
        if ((wave & 3) == 0) {
            #pragma unroll
            for (int i = 0; i < 4; ++i) {
                float s = ssum[i];
                s += __shfl_xor(s, 16, 64);
                s += __shfl_xor(s, 32, 64);
                if (lane < 16) sq1_s[wn + i * 16 + rrow] = s;
            }
        }
    }
    asm volatile("s_waitcnt lgkmcnt(0)" ::: "memory");
    __builtin_amdgcn_sched_barrier(0);
    __builtin_amdgcn_s_barrier();
    __builtin_amdgcn_sched_barrier(0);

    // ---- A region dead: stage B slices 0,1 into the ring ----
    // chunk = 1 KB = 2 rows of 512 B; 8 chunks/wave; src unit ^ (row&7)
    #define STAGE(mt_, boff_)                                                 \
        { _Pragma("unroll")                                                   \
          for (int c = 0; c < 8; ++c) {                                       \
            int ch_ = wave * 8 + c;                                           \
            int r_  = ch_ * 2 + (lane >> 5);                                  \
            async_copy16(pool + (boff_) + ch_ * 1024,                         \
                Bg + (size_t)((mt_) * 128 + r_) * 512                         \
                   + (((lane & 31) ^ (r_ & 7)) << 4)); } }

    STAGE(0, 0); STAGE(1, 65536);

    float rmin[4][4];
    #pragma unroll
    for (int i = 0; i < 4; ++i)
        #pragma unroll
        for (int r = 0; r < 4; ++r) rmin[i][r] = 3.0e38f;

    // ---- main loop: 8 m-tiles; ring-2 64 KB; waits 8/.../0 ----
    #pragma unroll 1
    for (int mt = 0; mt < 8; ++mt) {
        if (mt < 7) { asm volatile("s_waitcnt vmcnt(8)" ::: "memory"); }
        else        { asm volatile("s_waitcnt vmcnt(0)" ::: "memory"); }
        __builtin_amdgcn_s_barrier();
        __builtin_amdgcn_sched_barrier(0);

        const char* Bb = pool + (mt & 1) * 65536;
        floatx4 acc[4][2] = {};

        __builtin_amdgcn_s_setprio(1);
        #pragma unroll
        for (int kq = 0; kq < 8; ++kq) {
            short8 bfv[2];
            #pragma unroll
            for (int j = 0; j < 2; ++j) {
                int u = kq * 4 + krow;             // 16B unit in 512B row
                bfv[j] = *(const short8*)(Bb
                         + (size_t)(wm + j * 16 + rrow) * 512 + ((u ^ rx) << 4));
            }
            #pragma unroll
            for (int i = 0; i < 4; ++i)
                #pragma unroll
                for (int j = 0; j < 2; ++j)
                    acc[i][j] = __builtin_amdgcn_mfma_f32_16x16x32_bf16(
                        af[i][kq], bfv[j], acc[i][j], 0, 0, 0);
        }
        __builtin_amdgcn_s_setprio(0);

        asm volatile("s_waitcnt lgkmcnt(0)" ::: "memory");
        __builtin_amdgcn_sched_barrier(0);
        __builtin_amdgcn_s_barrier();
        if (mt < 6) STAGE(mt + 2, (mt & 1) * 65536);

        // ---- per-mt epilogue (regs + LDS only; no vmem) ----
        float s2v0 = sq2_s[mt * 128 + wm + lcol];
        float s2v1 = sq2_s[mt * 128 + wm + 16 + lcol];

        float cmin0 = 3.0e38f, cmin1 = 3.0e38f;
        #pragma unroll
        for (int i = 0; i < 4; ++i) {
            float4 s1q = *(const float4*)(&sq1_s[wn + i * 16 + lrow]);
            #pragma unroll
            for (int r = 0; r < 4; ++r) {
                float s1x = ((const float*)&s1q)[r];
                float d0 = fmaxf(s1x + s2v0 - 2.0f * acc[i][0][r], 0.0f);
                float d1 = fmaxf(s1x + s2v1 - 2.0f * acc[i][1][r], 0.0f);
                rmin[i][r] = fminf(rmin[i][r], fminf(d0, d1));
                cmin0 = fminf(cmin0, d0);
                cmin1 = fminf(cmin1, d1);
            }
        }
        cmin0 = fminf(cmin0, __shfl_xor(cmin0, 16, 64));
        cmin0 = fminf(cmin0, __shfl_xor(cmin0, 32, 64));
        cmin1 = fminf(cmin1, __shfl_xor(cmin1, 16, 64));
        cmin1 = fminf(cmin1, __shfl_xor(cmin1, 32, 64));
        if (lane < 16) {
            atomicMin(&cl_s[mt * 128 + wm + lcol],      __float_as_uint(cmin0));
            atomicMin(&cl_s[mt * 128 + wm + 16 + lcol], __float_as_uint(cmin1));
        }
    }

    // ---- rowmin combine + plain stores (block-exclusive outputs) ----
    #pragma unroll
    for (int i = 0; i < 4; ++i) {
        #pragma unroll
        for (int r = 0; r < 4; ++r) {
            float v = rmin[i][r];
            #pragma unroll
            for (int off = 1; off < 16; off <<= 1)
                v = fminf(v, __shfl_xor(v, off, 64));
            if (lcol == 0)
                atomicMin(&rl_s[wn + i * 16 + lrow + r], __float_as_uint(v));
        }
    }
    __syncthreads();

    unsigned int* cp = colpart + ((size_t)b * 8 + tile) * 1024;
    cp[tid]       = cl_s[tid];
    cp[tid + 512] = cl_s[tid + 512];
    if (tid < 128) rowmin[b * NN + n0 + tid] = rl_s[tid];
    #undef STAGE
}

// ---------------------------------------------------------------------------
// out[b] = (sum_n rowmin + sum_m min_tile colpart) / 1024
// ---------------------------------------------------------------------------
__global__ __launch_bounds__(256) void finalize_kernel(
        const unsigned int* __restrict__ rowmin,
        const unsigned int* __restrict__ colpart,
        float* __restrict__ out) {
    int b = blockIdx.x;
    int tid = threadIdx.x;
    float s = 0.0f;
    #pragma unroll
    for (int t = 0; t < 4; ++t) {
        int m = tid + t * 256;
        s += __uint_as_float(rowmin[b * NN + m]);
        unsigned int v = colpart[(size_t)b * 8192 + m];
        #pragma unroll
        for (int q = 1; q < 8; ++q)
            v = min(v, colpart[(size_t)b * 8192 + q * 1024 + m]);
        s += __uint_as_float(v);
    }
    #pragma unroll
    for (int off = 32; off; off >>= 1) s += __shfl_xor(s, off, 64);
    __shared__ float wsum[4];
    if ((tid & 63) == 0) wsum[tid >> 6] = s;
    __syncthreads();
    if (tid == 0) out[b] = (wsum[0] + wsum[1] + wsum[2] + wsum[3]) * (1.0f / 1024.0f);
}

// ---------------------------------------------------------------------------
extern "C" void kernel_launch(void* const* d_in, const int* in_sizes, int n_in,
                              void* d_out, int out_size, void* d_ws, size_t ws_size,
                              hipStream_t stream) {
    const float* h1 = (const float*)d_in[0];
    const float* h2 = (const float*)d_in[1];
    float* out = (float*)d_out;

    char* ws = (char*)d_ws;
    unsigned short* h2b = (unsigned short*)ws;                    // 16 MB
    float* sq2          = (float*)(ws + (size_t)16 * 1024 * 1024);
    unsigned int* rowmin  = (unsigned int*)(sq2 + BB * MM);       // 128 KB
    unsigned int* colpart = rowmin + BB * NN;                     // 1 MB

    hipLaunchKernelGGL(convert_kernel, dim3(4096), dim3(256), 0, stream,
                       h2, h2b, sq2);

    hipLaunchKernelGGL(gemm_kernel, dim3(BB, 8), dim3(512), 0, stream,
                       h1, h2b, sq2, rowmin, colpart);

    hipLaunchKernelGGL(finalize_kernel, dim3(BB), dim3(256), 0, stream,
                       rowmin, colpart, out);
}